// Round 5
// baseline (124.802 us; speedup 1.0000x reference)
//
#include <hip/hip_runtime.h>
#include <hip/hip_bf16.h>
#include <cstdint>

#define NB   128
#define CD   64
#define LD   4096
#define KC   100
#define KT   7            // 7 k-tiles of 16 -> 112 padded clusters
#define KR   (KT * 16)    // 112
#define AKP  72           // akl row stride: 144 B rows, keeps b128 reads 16B-aligned
#define LSPLIT 8
#define LCH  (LD / LSPLIT) // 512 l's per block
#define ITERS (LCH / 64)   // 8 inner iters of 64 l

typedef __attribute__((ext_vector_type(8))) short bf16x8;
typedef __attribute__((ext_vector_type(4))) float f32x4;

__device__ __forceinline__ short bfbits(float f) {
    __hip_bfloat16 h = __float2bfloat16(f);
    return *reinterpret_cast<short*>(&h);
}
__device__ __forceinline__ float bffloat(short s) {
    __hip_bfloat16 h = *reinterpret_cast<__hip_bfloat16*>(&s);
    return __bfloat162float(h);
}

// Precompute W fragments (bf16 hi/lo, MFMA A-layout, zero-padded rows) + padded bias.
// wfrag[((t*2+h)*2+s)*64 + lane] = 8 bf16: W[t*16 + (lane&15)][h*32 + (lane>>4)*8 + 0..7]
__global__ void k_prep(const float* __restrict__ w, const float* __restrict__ b,
                       uint4* __restrict__ wfrag, float* __restrict__ b_pad)
{
    const int tid = threadIdx.x;
    if (tid < 128) b_pad[tid] = (tid < KC) ? b[tid] : -1e30f;
    if (tid < 64) {
        const int r16 = tid & 15, gg = tid >> 4;
        for (int t = 0; t < KT; ++t) {
            const int k = t * 16 + r16;
            for (int h = 0; h < 2; ++h) {
                short hi8[8], lo8[8];
                for (int j = 0; j < 8; ++j) {
                    const int c = h * 32 + gg * 8 + j;
                    float v = (k < KC) ? w[k * CD + c] : 0.f;
                    short hb = bfbits(v);
                    hi8[j] = hb;
                    lo8[j] = bfbits(v - bffloat(hb));
                }
                wfrag[((t * 2 + h) * 2 + 0) * 64 + tid] = *reinterpret_cast<uint4*>(hi8);
                wfrag[((t * 2 + h) * 2 + 1) * 64 + tid] = *reinterpret_cast<uint4*>(lo8);
            }
        }
    }
}

// Fused: normalize+logits (MFMA) + softmax + agg (MFMA) + asum (LDS row-sum).
// W fragments read from global each iter (28.7KB, L1-resident) -> LDS = 32KB -> 4 blocks/CU.
__global__ __launch_bounds__(256, 4) void k_fused(
    const float* __restrict__ x, const uint4* __restrict__ wfrag,
    const float* __restrict__ b_pad,
    float* __restrict__ agg_pT, float* __restrict__ asum_pT, int n0)
{
    __shared__ float xs[CD][65];                          // x tile [c][l], fp32 (16640 B)
    __shared__ __align__(16) __hip_bfloat16 akl[KR][AKP]; // a tile [k][l] (16128 B)

    const int tid  = threadIdx.x;
    const int lane = tid & 63;
    const int wv   = tid >> 6;
    const int lloc = lane & 15;
    const int g    = lane >> 4;

    const int nn = blockIdx.x >> 3;
    const int ls = blockIdx.x & 7;
    const int n  = n0 + nn;
    const float* xb = x + (size_t)n * CD * LD + ls * LCH;

    // bias preload (this lane's 4 k's per tile)
    const float4* bp4 = reinterpret_cast<const float4*>(b_pad);
    float4 bv[KT];
#pragma unroll
    for (int t = 0; t < KT; ++t) bv[t] = bp4[t * 4 + g];

    f32x4 aagg[KT];
#pragma unroll
    for (int mt = 0; mt < KT; ++mt) aagg[mt] = (f32x4){0.f, 0.f, 0.f, 0.f};
    float asl = 0.f;   // asum accumulator (threads tid<KR own row k=tid)

    // prefetch iter 0's x tile into regs
    float4 pv[4];
#pragma unroll
    for (int i = 0; i < 4; ++i) {
        int idx = tid + i * 256, c = idx >> 4, lq = idx & 15;
        pv[i] = *reinterpret_cast<const float4*>(xb + (size_t)c * LD + lq * 4);
    }

    const bf16x8* wfp = reinterpret_cast<const bf16x8*>(wfrag);
    const int lw = wv * 16 + lloc;    // this lane's l (logits/softmax phase)
    const int cb = wv * 16 + lloc;    // this lane's c (agg phase)

    for (int it = 0; it < ITERS; ++it) {
        // defeat CSE/hoist of the loop-invariant W loads (keeps them per-iter, L1-hit)
        asm volatile("" : "+v"(wfp));

        __syncthreads();                               // S0: xs/akl free
        // write staged x tile
#pragma unroll
        for (int i = 0; i < 4; ++i) {
            int idx = tid + i * 256, c = idx >> 4, lq = idx & 15;
            xs[c][lq * 4 + 0] = pv[i].x; xs[c][lq * 4 + 1] = pv[i].y;
            xs[c][lq * 4 + 2] = pv[i].z; xs[c][lq * 4 + 3] = pv[i].w;
        }
        __syncthreads();                               // S1: xs ready

        // logits B-frags (x column hi/lo) + sumsq-over-c via shfl
        float ss = 0.f;
        bf16x8 bhi0, blo0, bhi1, blo1;
#pragma unroll
        for (int j = 0; j < 8; ++j) {
            float v0 = xs[g * 8 + j][lw];
            ss = fmaf(v0, v0, ss);
            short h0 = bfbits(v0);
            bhi0[j] = h0; blo0[j] = bfbits(v0 - bffloat(h0));
            float v1 = xs[32 + g * 8 + j][lw];
            ss = fmaf(v1, v1, ss);
            short h1 = bfbits(v1);
            bhi1[j] = h1; blo1[j] = bfbits(v1 - bffloat(h1));
        }
        ss += __shfl_xor(ss, 16);
        ss += __shfl_xor(ss, 32);
        const float rn = 1.0f / fmaxf(sqrtf(ss), 1e-12f);

        // logits MFMA (split precision: hh + hl + lh); W frags from global (L1-hot)
        f32x4 acc[KT];
#pragma unroll
        for (int t = 0; t < KT; ++t) acc[t] = (f32x4){0.f, 0.f, 0.f, 0.f};
#pragma unroll
        for (int t = 0; t < KT; ++t) {
            bf16x8 wh0 = wfp[((t * 2 + 0) * 2 + 0) * 64 + lane];
            bf16x8 wl0 = wfp[((t * 2 + 0) * 2 + 1) * 64 + lane];
            bf16x8 wh1 = wfp[((t * 2 + 1) * 2 + 0) * 64 + lane];
            bf16x8 wl1 = wfp[((t * 2 + 1) * 2 + 1) * 64 + lane];
            acc[t] = __builtin_amdgcn_mfma_f32_16x16x32_bf16(wh0, bhi0, acc[t], 0, 0, 0);
            acc[t] = __builtin_amdgcn_mfma_f32_16x16x32_bf16(wh1, bhi1, acc[t], 0, 0, 0);
            acc[t] = __builtin_amdgcn_mfma_f32_16x16x32_bf16(wh0, blo0, acc[t], 0, 0, 0);
            acc[t] = __builtin_amdgcn_mfma_f32_16x16x32_bf16(wh1, blo1, acc[t], 0, 0, 0);
            acc[t] = __builtin_amdgcn_mfma_f32_16x16x32_bf16(wl0, bhi0, acc[t], 0, 0, 0);
            acc[t] = __builtin_amdgcn_mfma_f32_16x16x32_bf16(wl1, bhi1, acc[t], 0, 0, 0);
        }

        // softmax over k (per l). D: col(l)=lane&15, row(k)=g*4+r (+16t)
        float m = -3.0e38f;
#pragma unroll
        for (int t = 0; t < KT; ++t) {
            acc[t][0] = fmaf(acc[t][0], rn, bv[t].x);
            acc[t][1] = fmaf(acc[t][1], rn, bv[t].y);
            acc[t][2] = fmaf(acc[t][2], rn, bv[t].z);
            acc[t][3] = fmaf(acc[t][3], rn, bv[t].w);
            m = fmaxf(m, fmaxf(fmaxf(acc[t][0], acc[t][1]), fmaxf(acc[t][2], acc[t][3])));
        }
        m = fmaxf(m, __shfl_xor(m, 16));
        m = fmaxf(m, __shfl_xor(m, 32));
        float s = 0.f;
#pragma unroll
        for (int t = 0; t < KT; ++t) {
#pragma unroll
            for (int r = 0; r < 4; ++r) {
                float e = __expf(acc[t][r] - m);
                acc[t][r] = e;
                s += e;
            }
        }
        s += __shfl_xor(s, 16);
        s += __shfl_xor(s, 32);
        const float inv = 1.0f / s;

        // a -> LDS [k][l] bf16, plain indexing
#pragma unroll
        for (int r = 0; r < 4; ++r) {
#pragma unroll
            for (int t = 0; t < KT; ++t)
                akl[t * 16 + g * 4 + r][lw] = __float2bfloat16(acc[t][r] * inv);
        }

        // prefetch next iter's x during the MFMA-heavy agg phase
        if (it + 1 < ITERS) {
#pragma unroll
            for (int i = 0; i < 4; ++i) {
                int idx = tid + i * 256, c = idx >> 4, lq = idx & 15;
                pv[i] = *reinterpret_cast<const float4*>(
                    xb + (it + 1) * 64 + (size_t)c * LD + lq * 4);
            }
        }
        __syncthreads();                               // S3: akl ready

        // asum: thread tid<112 sums its row k=tid over this tile's 64 l's
        if (tid < KR) {
            const bf16x8* rp = reinterpret_cast<const bf16x8*>(&akl[tid][0]);
            float rs = 0.f;
#pragma unroll
            for (int q = 0; q < 8; ++q) {
                bf16x8 v = rp[q];
#pragma unroll
                for (int j = 0; j < 8; ++j) rs += bffloat(v[j]);
            }
            asl += rs;
        }

        // agg MFMA: A = a frags (k rows), B = x hi/lo (c cols), redn = l
#pragma unroll
        for (int h = 0; h < 2; ++h) {
            const float* xrow = &xs[cb][h * 32 + g * 8];
            bf16x8 xh, xl;
#pragma unroll
            for (int j = 0; j < 8; ++j) {
                float v = xrow[j];
                short hb = bfbits(v);
                xh[j] = hb; xl[j] = bfbits(v - bffloat(hb));
            }
#pragma unroll
            for (int mt = 0; mt < KT; ++mt) {
                bf16x8 af = *reinterpret_cast<const bf16x8*>(
                    &akl[mt * 16 + lloc][h * 32 + g * 8]);
                aagg[mt] = __builtin_amdgcn_mfma_f32_16x16x32_bf16(af, xh, aagg[mt], 0, 0, 0);
                aagg[mt] = __builtin_amdgcn_mfma_f32_16x16x32_bf16(af, xl, aagg[mt], 0, 0, 0);
            }
        }
    }

    // write partials: agg_pT[nls][c][128kpad], asum_pT[nls][112]
    const size_t nls = (size_t)nn * LSPLIT + ls;
    float* ap = agg_pT + (nls * 64 + cb) * 128 + g * 4;
#pragma unroll
    for (int mt = 0; mt < KT; ++mt)
        *reinterpret_cast<f32x4*>(ap + mt * 16) = aagg[mt];
    if (tid < KR) asum_pT[nls * KR + tid] = asl;
}

// Final: reduce partials, subtract centroid*asum, intra-norm over C, global L2 norm.
__global__ __launch_bounds__(256, 1) void k_final(
    const float* __restrict__ agg_pT, const float* __restrict__ asum_pT,
    const float* __restrict__ cent, float* __restrict__ out, int n0)
{
    __shared__ float vbuf[KC][65];
    __shared__ float asum_s[KR];
    __shared__ float rn_s[KC];
    __shared__ float red[256];

    const int tid = threadIdx.x;
    const int nn  = blockIdx.x;
    const int n   = n0 + nn;
    const size_t nb8 = (size_t)nn * LSPLIT;

    if (tid < KR) {
        float s = 0.f;
#pragma unroll
        for (int ls = 0; ls < LSPLIT; ++ls)
            s += asum_pT[(nb8 + ls) * KR + tid];
        asum_s[tid] = s;
    }
    __syncthreads();

    for (int idx = tid; idx < 64 * 128; idx += 256) {
        int c = idx >> 7, k = idx & 127;
        if (k < KC) {
            float s = 0.f;
#pragma unroll
            for (int ls = 0; ls < LSPLIT; ++ls)
                s += agg_pT[((nb8 + ls) * 64 + c) * 128 + k];
            vbuf[k][c] = fmaf(-cent[k * CD + c], asum_s[k], s);
        }
    }
    __syncthreads();

    if (tid < KC) {
        float ssq = 0.f;
#pragma unroll 8
        for (int c = 0; c < CD; ++c) {
            float v = vbuf[tid][c];
            ssq = fmaf(v, v, ssq);
        }
        rn_s[tid] = 1.0f / fmaxf(sqrtf(ssq), 1e-12f);
    }
    __syncthreads();

    float gp = 0.f;
    for (int idx = tid; idx < KC * CD; idx += 256) {
        int k = idx >> 6, c = idx & 63;
        float v = vbuf[k][c] * rn_s[k];
        gp = fmaf(v, v, gp);
    }
    red[tid] = gp;
    __syncthreads();
    for (int off = 128; off > 0; off >>= 1) {
        if (tid < off) red[tid] += red[tid + off];
        __syncthreads();
    }
    const float gnorm = 1.0f / fmaxf(sqrtf(red[0]), 1e-12f);

    float* op = out + (size_t)n * (KC * CD);
    for (int idx = tid; idx < KC * CD; idx += 256) {
        int k = idx >> 6, c = idx & 63;
        op[idx] = vbuf[k][c] * rn_s[k] * gnorm;
    }
}

extern "C" void kernel_launch(void* const* d_in, const int* in_sizes, int n_in,
                              void* d_out, int out_size, void* d_ws, size_t ws_size,
                              hipStream_t stream)
{
    const float* x  = (const float*)d_in[0];
    const float* w  = (const float*)d_in[1];
    const float* b  = (const float*)d_in[2];
    const float* ct = (const float*)d_in[3];
    float* out = (float*)d_out;

    char* wsp = (char*)d_ws;
    uint4* wfrag = (uint4*)wsp;                 // 28672 B
    float* b_pad = (float*)(wsp + 28672);       // 512 B
    char* chunk  = wsp + 32768;

    const size_t agg_per_n  = (size_t)LSPLIT * 64 * 128 * 4; // 262144 B
    const size_t asum_per_n = (size_t)LSPLIT * KR * 4;       // 3584 B
    const size_t per_n = agg_per_n + asum_per_n;

    size_t avail = ws_size > 32768 ? ws_size - 32768 : 0;
    int nc = (int)(avail / per_n);
    if (nc < 1) nc = 1;
    if (nc > NB) nc = NB;

    float* agg_pT  = (float*)chunk;
    float* asum_pT = (float*)(chunk + agg_per_n * (size_t)nc);

    k_prep<<<1, 128, 0, stream>>>(w, b, wfrag, b_pad);
    for (int n0 = 0; n0 < NB; n0 += nc) {
        int cn = NB - n0; if (cn > nc) cn = nc;
        k_fused<<<cn * LSPLIT, 256, 0, stream>>>(x, wfrag, b_pad, agg_pT, asum_pT, n0);
        k_final<<<cn, 256, 0, stream>>>(agg_pT, asum_pT, ct, out, n0);
    }
}

// Round 6
// 100.097 us; speedup vs baseline: 1.2468x; 1.2468x over previous
//
#include <hip/hip_runtime.h>
#include <hip/hip_bf16.h>
#include <cstdint>

#define NB   128
#define CD   64
#define LD   4096
#define KC   100
#define KT   7            // 7 k-tiles of 16 -> 112 padded clusters
#define KR   (KT * 16)    // 112
#define AKP  72           // akl row stride: 144 B rows, keeps b128 reads 16B-aligned
#define LSPLIT 8
#define LCH  (LD / LSPLIT) // 512 l's per block
#define ITERS (LCH / 64)   // 8 inner iters of 64 l

typedef __attribute__((ext_vector_type(8))) short bf16x8;
typedef __attribute__((ext_vector_type(4))) float f32x4;

__device__ __forceinline__ short bfbits(float f) {
    __hip_bfloat16 h = __float2bfloat16(f);
    return *reinterpret_cast<short*>(&h);
}
__device__ __forceinline__ float bffloat(short s) {
    __hip_bfloat16 h = *reinterpret_cast<__hip_bfloat16*>(&s);
    return __bfloat162float(h);
}

// Precompute W fragments (bf16 hi/lo, MFMA A-layout, zero-padded rows) + padded bias.
// wfrag[((t*2+h)*2+s)*64 + lane] = 8 bf16: W[t*16 + (lane&15)][h*32 + (lane>>4)*8 + 0..7]
__global__ void k_prep(const float* __restrict__ w, const float* __restrict__ b,
                       uint4* __restrict__ wfrag, float* __restrict__ b_pad)
{
    const int tid = threadIdx.x;
    if (tid < 128) b_pad[tid] = (tid < KC) ? b[tid] : -1e30f;
    if (tid < 64) {
        const int r16 = tid & 15, gg = tid >> 4;
        for (int t = 0; t < KT; ++t) {
            const int k = t * 16 + r16;
            for (int h = 0; h < 2; ++h) {
                short hi8[8], lo8[8];
                for (int j = 0; j < 8; ++j) {
                    const int c = h * 32 + gg * 8 + j;
                    float v = (k < KC) ? w[k * CD + c] : 0.f;
                    short hb = bfbits(v);
                    hi8[j] = hb;
                    lo8[j] = bfbits(v - bffloat(hb));
                }
                wfrag[((t * 2 + h) * 2 + 0) * 64 + tid] = *reinterpret_cast<uint4*>(hi8);
                wfrag[((t * 2 + h) * 2 + 1) * 64 + tid] = *reinterpret_cast<uint4*>(lo8);
            }
        }
    }
}

// Fused: normalize+logits (MFMA) + softmax + agg (MFMA) + asum (LDS row-sum).
// x read straight from global (coalesced fragment patterns, L1/L2-hot on 2nd touch).
// LDS = W frags (28.7KB) + akl (16.1KB) = 44.8KB -> 3 blocks/CU.
__global__ __launch_bounds__(256, 3) void k_fused(
    const float* __restrict__ x, const uint4* __restrict__ wfrag,
    const float* __restrict__ b_pad,
    float* __restrict__ agg_pT, float* __restrict__ asum_pT, int n0)
{
    __shared__ __align__(16) __hip_bfloat16 akl[KR][AKP]; // a tile [k][l] (16128 B)
    __shared__ __align__(16) uint4 wlds[KT * 2 * 2 * 64]; // W fragments (28672 B)

    const int tid  = threadIdx.x;
    const int lane = tid & 63;
    const int wv   = tid >> 6;
    const int lloc = lane & 15;
    const int g    = lane >> 4;

    // one-time: W fragments -> LDS; first consumed after the first barrier below
    for (int i = tid; i < KT * 2 * 2 * 64; i += 256) wlds[i] = wfrag[i];

    const int nn = blockIdx.x >> 3;
    const int ls = blockIdx.x & 7;
    const int n  = n0 + nn;
    const float* xb = x + (size_t)n * CD * LD + ls * LCH;

    // bias preload (this lane's 4 k's per tile)
    const float4* bp4 = reinterpret_cast<const float4*>(b_pad);
    float4 bv[KT];
#pragma unroll
    for (int t = 0; t < KT; ++t) bv[t] = bp4[t * 4 + g];

    f32x4 aagg[KT];
#pragma unroll
    for (int mt = 0; mt < KT; ++mt) aagg[mt] = (f32x4){0.f, 0.f, 0.f, 0.f};
    float asl = 0.f;   // asum accumulator (threads tid<KR own row k=tid)

    const bf16x8* wfp = reinterpret_cast<const bf16x8*>(wlds);
    const int lw = wv * 16 + lloc;    // this lane's l (logits/softmax phase)
    const int cb = wv * 16 + lloc;    // this lane's c (agg phase)

    __syncthreads();                  // wlds ready (once)

    for (int it = 0; it < ITERS; ++it) {
        // logits B-frags: x columns straight from global (coalesced across lloc)
        const float* xcol = xb + it * 64 + lw;
        float ss = 0.f;
        bf16x8 bhi0, blo0, bhi1, blo1;
#pragma unroll
        for (int j = 0; j < 8; ++j) {
            float v0 = xcol[(size_t)(g * 8 + j) * LD];
            ss = fmaf(v0, v0, ss);
            short h0 = bfbits(v0);
            bhi0[j] = h0; blo0[j] = bfbits(v0 - bffloat(h0));
            float v1 = xcol[(size_t)(32 + g * 8 + j) * LD];
            ss = fmaf(v1, v1, ss);
            short h1 = bfbits(v1);
            bhi1[j] = h1; blo1[j] = bfbits(v1 - bffloat(h1));
        }
        ss += __shfl_xor(ss, 16);
        ss += __shfl_xor(ss, 32);
        const float rn = 1.0f / fmaxf(sqrtf(ss), 1e-12f);

        // logits MFMA (split precision: hh + hl + lh); W frags from LDS
        f32x4 acc[KT];
#pragma unroll
        for (int t = 0; t < KT; ++t) acc[t] = (f32x4){0.f, 0.f, 0.f, 0.f};
#pragma unroll
        for (int t = 0; t < KT; ++t) {
            bf16x8 wh0 = wfp[((t * 2 + 0) * 2 + 0) * 64 + lane];
            bf16x8 wl0 = wfp[((t * 2 + 0) * 2 + 1) * 64 + lane];
            bf16x8 wh1 = wfp[((t * 2 + 1) * 2 + 0) * 64 + lane];
            bf16x8 wl1 = wfp[((t * 2 + 1) * 2 + 1) * 64 + lane];
            acc[t] = __builtin_amdgcn_mfma_f32_16x16x32_bf16(wh0, bhi0, acc[t], 0, 0, 0);
            acc[t] = __builtin_amdgcn_mfma_f32_16x16x32_bf16(wh1, bhi1, acc[t], 0, 0, 0);
            acc[t] = __builtin_amdgcn_mfma_f32_16x16x32_bf16(wh0, blo0, acc[t], 0, 0, 0);
            acc[t] = __builtin_amdgcn_mfma_f32_16x16x32_bf16(wh1, blo1, acc[t], 0, 0, 0);
            acc[t] = __builtin_amdgcn_mfma_f32_16x16x32_bf16(wl0, bhi0, acc[t], 0, 0, 0);
            acc[t] = __builtin_amdgcn_mfma_f32_16x16x32_bf16(wl1, bhi1, acc[t], 0, 0, 0);
        }

        // softmax over k (per l). D: col(l)=lane&15, row(k)=g*4+r (+16t)
        float m = -3.0e38f;
#pragma unroll
        for (int t = 0; t < KT; ++t) {
            acc[t][0] = fmaf(acc[t][0], rn, bv[t].x);
            acc[t][1] = fmaf(acc[t][1], rn, bv[t].y);
            acc[t][2] = fmaf(acc[t][2], rn, bv[t].z);
            acc[t][3] = fmaf(acc[t][3], rn, bv[t].w);
            m = fmaxf(m, fmaxf(fmaxf(acc[t][0], acc[t][1]), fmaxf(acc[t][2], acc[t][3])));
        }
        m = fmaxf(m, __shfl_xor(m, 16));
        m = fmaxf(m, __shfl_xor(m, 32));
        float s = 0.f;
#pragma unroll
        for (int t = 0; t < KT; ++t) {
#pragma unroll
            for (int r = 0; r < 4; ++r) {
                float e = __expf(acc[t][r] - m);
                acc[t][r] = e;
                s += e;
            }
        }
        s += __shfl_xor(s, 16);
        s += __shfl_xor(s, 32);
        const float inv = 1.0f / s;

        __syncthreads();        // prev iter's akl consumers (asum/agg) done

        // a -> LDS [k][l] bf16, plain indexing
#pragma unroll
        for (int r = 0; r < 4; ++r) {
#pragma unroll
            for (int t = 0; t < KT; ++t)
                akl[t * 16 + g * 4 + r][lw] = __float2bfloat16(acc[t][r] * inv);
        }
        __syncthreads();        // akl ready

        // asum: thread tid<112 sums its row k=tid over this tile's 64 l's
        if (tid < KR) {
            const bf16x8* rp = reinterpret_cast<const bf16x8*>(&akl[tid][0]);
            float rs = 0.f;
#pragma unroll
            for (int q = 0; q < 8; ++q) {
                bf16x8 v = rp[q];
#pragma unroll
                for (int j = 0; j < 8; ++j) rs += bffloat(v[j]);
            }
            asl += rs;
        }

        // agg MFMA: A = a frags (k rows, LDS), B = x hi/lo (c cols, global 32B/lane)
#pragma unroll
        for (int h = 0; h < 2; ++h) {
            const float* xrow = xb + (size_t)cb * LD + it * 64 + h * 32 + g * 8;
            float4 xr0 = *reinterpret_cast<const float4*>(xrow);
            float4 xr1 = *reinterpret_cast<const float4*>(xrow + 4);
            float xv8[8] = {xr0.x, xr0.y, xr0.z, xr0.w, xr1.x, xr1.y, xr1.z, xr1.w};
            bf16x8 xh, xl;
#pragma unroll
            for (int j = 0; j < 8; ++j) {
                float v = xv8[j];
                short hb = bfbits(v);
                xh[j] = hb; xl[j] = bfbits(v - bffloat(hb));
            }
#pragma unroll
            for (int mt = 0; mt < KT; ++mt) {
                bf16x8 af = *reinterpret_cast<const bf16x8*>(
                    &akl[mt * 16 + lloc][h * 32 + g * 8]);
                aagg[mt] = __builtin_amdgcn_mfma_f32_16x16x32_bf16(af, xh, aagg[mt], 0, 0, 0);
                aagg[mt] = __builtin_amdgcn_mfma_f32_16x16x32_bf16(af, xl, aagg[mt], 0, 0, 0);
            }
        }
    }

    // write partials: agg_pT[nls][c][128kpad], asum_pT[nls][112]
    const size_t nls = (size_t)nn * LSPLIT + ls;
    float* ap = agg_pT + (nls * 64 + cb) * 128 + g * 4;
#pragma unroll
    for (int mt = 0; mt < KT; ++mt)
        *reinterpret_cast<f32x4*>(ap + mt * 16) = aagg[mt];
    if (tid < KR) asum_pT[nls * KR + tid] = asl;
}

// Final: reduce partials, subtract centroid*asum, intra-norm over C, global L2 norm.
__global__ __launch_bounds__(256, 1) void k_final(
    const float* __restrict__ agg_pT, const float* __restrict__ asum_pT,
    const float* __restrict__ cent, float* __restrict__ out, int n0)
{
    __shared__ float vbuf[KC][65];
    __shared__ float asum_s[KR];
    __shared__ float rn_s[KC];
    __shared__ float red[256];

    const int tid = threadIdx.x;
    const int nn  = blockIdx.x;
    const int n   = n0 + nn;
    const size_t nb8 = (size_t)nn * LSPLIT;

    if (tid < KR) {
        float s = 0.f;
#pragma unroll
        for (int ls = 0; ls < LSPLIT; ++ls)
            s += asum_pT[(nb8 + ls) * KR + tid];
        asum_s[tid] = s;
    }
    __syncthreads();

    for (int idx = tid; idx < 64 * 128; idx += 256) {
        int c = idx >> 7, k = idx & 127;
        if (k < KC) {
            float s = 0.f;
#pragma unroll
            for (int ls = 0; ls < LSPLIT; ++ls)
                s += agg_pT[((nb8 + ls) * 64 + c) * 128 + k];
            vbuf[k][c] = fmaf(-cent[k * CD + c], asum_s[k], s);
        }
    }
    __syncthreads();

    if (tid < KC) {
        float ssq = 0.f;
#pragma unroll 8
        for (int c = 0; c < CD; ++c) {
            float v = vbuf[tid][c];
            ssq = fmaf(v, v, ssq);
        }
        rn_s[tid] = 1.0f / fmaxf(sqrtf(ssq), 1e-12f);
    }
    __syncthreads();

    float gp = 0.f;
    for (int idx = tid; idx < KC * CD; idx += 256) {
        int k = idx >> 6, c = idx & 63;
        float v = vbuf[k][c] * rn_s[k];
        gp = fmaf(v, v, gp);
    }
    red[tid] = gp;
    __syncthreads();
    for (int off = 128; off > 0; off >>= 1) {
        if (tid < off) red[tid] += red[tid + off];
        __syncthreads();
    }
    const float gnorm = 1.0f / fmaxf(sqrtf(red[0]), 1e-12f);

    float* op = out + (size_t)n * (KC * CD);
    for (int idx = tid; idx < KC * CD; idx += 256) {
        int k = idx >> 6, c = idx & 63;
        op[idx] = vbuf[k][c] * rn_s[k] * gnorm;
    }
}

extern "C" void kernel_launch(void* const* d_in, const int* in_sizes, int n_in,
                              void* d_out, int out_size, void* d_ws, size_t ws_size,
                              hipStream_t stream)
{
    const float* x  = (const float*)d_in[0];
    const float* w  = (const float*)d_in[1];
    const float* b  = (const float*)d_in[2];
    const float* ct = (const float*)d_in[3];
    float* out = (float*)d_out;

    char* wsp = (char*)d_ws;
    uint4* wfrag = (uint4*)wsp;                 // 28672 B
    float* b_pad = (float*)(wsp + 28672);       // 512 B
    char* chunk  = wsp + 32768;

    const size_t agg_per_n  = (size_t)LSPLIT * 64 * 128 * 4; // 262144 B
    const size_t asum_per_n = (size_t)LSPLIT * KR * 4;       // 3584 B
    const size_t per_n = agg_per_n + asum_per_n;

    size_t avail = ws_size > 32768 ? ws_size - 32768 : 0;
    int nc = (int)(avail / per_n);
    if (nc < 1) nc = 1;
    if (nc > NB) nc = NB;

    float* agg_pT  = (float*)chunk;
    float* asum_pT = (float*)(chunk + agg_per_n * (size_t)nc);

    k_prep<<<1, 128, 0, stream>>>(w, b, wfrag, b_pad);
    for (int n0 = 0; n0 < NB; n0 += nc) {
        int cn = NB - n0; if (cn > nc) cn = nc;
        k_fused<<<cn * LSPLIT, 256, 0, stream>>>(x, wfrag, b_pad, agg_pT, asum_pT, n0);
        k_final<<<cn, 256, 0, stream>>>(agg_pT, asum_pT, ct, out, n0);
    }
}